// Round 1
// baseline (8838.507 us; speedup 1.0000x reference)
//
#include <hip/hip_runtime.h>
#include <hip/hip_bf16.h>

// Neural CDE forward: B=32, Amax=64 -> N=2048 agents, T=16 knots, D=10, E=128, H=512.
// Strategy (fp32 correctness baseline):
//  - rows are independent across the whole ODE -> persistent block-local integration,
//    256 blocks x 8 rows, z kept in LDS for all 15 RK4 steps (60 vf evals), no grid sync.
//  - weights pre-transposed to k-major in ws for coalesced loads; spline derivative
//    precomputed into a 46-point table (3 interior points per step + final u=1 point).

#define N_AG   2048
#define D_IN   10
#define E_DIM  128
#define H_DIM  512
#define ED_DIM 1280
#define NPTS   46
#define RROWS  8

// ws layout (floats)
#define OFF_W0T 0                          // 128 x 512
#define OFF_W1T (OFF_W0T + 128 * 512)      // 512 x 512
#define OFF_W2T (OFF_W1T + 512 * 512)      // 512 x 512
#define OFF_W3T (OFF_W2T + 512 * 512)      // 512 x 1280
#define OFF_DX  (OFF_W3T + 512 * 1280)     // 46 x 2048 x 10

__global__ void transpose_k(const float* __restrict__ W, float* __restrict__ Wt,
                            int O, int I) {
  int idx = blockIdx.x * blockDim.x + threadIdx.x;
  if (idx < O * I) {
    int o = idx / I, i = idx - o * I;
    Wt[i * O + o] = W[idx];
  }
}

// Natural cubic spline (t = 0..15, h = 1): Thomas solve per (n,d), then emit the
// derivative table dX[p][n][d] for the 46 distinct RK4 evaluation points.
__global__ void spline_dx_k(const float* __restrict__ x, float* __restrict__ dX) {
  int idx = blockIdx.x * blockDim.x + threadIdx.x;
  if (idx >= N_AG * D_IN) return;
  int n = idx / D_IN;
  int d = idx - n * D_IN;

  float xv[16];
#pragma unroll
  for (int t = 0; t < 16; ++t) xv[t] = x[n * 160 + t * 10 + d];

  // interior system i=1..14:  M[i-1] + 4 M[i] + M[i+1] = 6*(x[i+1]-2x[i]+x[i-1]), M0=M15=0
  float cp[15], dp[15], M[16];
  {
    float rhs = 6.0f * (xv[2] - 2.0f * xv[1] + xv[0]);
    cp[1] = 0.25f;
    dp[1] = rhs * 0.25f;
#pragma unroll
    for (int i = 2; i <= 14; ++i) {
      rhs = 6.0f * (xv[i + 1] - 2.0f * xv[i] + xv[i - 1]);
      float m = 1.0f / (4.0f - cp[i - 1]);
      cp[i] = m;
      dp[i] = (rhs - dp[i - 1]) * m;
    }
    M[0] = 0.0f; M[15] = 0.0f;
    M[14] = dp[14];
#pragma unroll
    for (int i = 13; i >= 1; --i) M[i] = dp[i] - cp[i] * M[i + 1];
  }

#pragma unroll
  for (int p = 0; p < NPTS; ++p) {
    int i; float u;
    if (p < 45) { i = p / 3; u = (float)(p % 3) * (1.0f / 3.0f); }
    else        { i = 14;    u = 1.0f; }
    float b = (xv[i + 1] - xv[i]) - (2.0f * M[i] + M[i + 1]) * (1.0f / 6.0f);
    dX[p * (N_AG * D_IN) + idx] = b + M[i] * u + (M[i + 1] - M[i]) * (u * u * 0.5f);
  }
}

template <int K, int NCOL, bool RELU>
__device__ __forceinline__ void layer_fc(const float* __restrict__ Wt,   // K x NCOL
                                         const float* __restrict__ bias, // NCOL
                                         const float (*__restrict__ inT)[RROWS],
                                         float (*__restrict__ outT)[RROWS],
                                         int tid) {
  for (int c = tid; c < NCOL; c += 512) {
    float a0 = 0, a1 = 0, a2 = 0, a3 = 0, a4 = 0, a5 = 0, a6 = 0, a7 = 0;
    const float* wp = Wt + c;
#pragma unroll 8
    for (int k = 0; k < K; ++k) {
      float w = wp[k * NCOL];
      float4 lo = *(const float4*)(&inT[k][0]);   // same addr all lanes -> LDS broadcast
      float4 hi = *(const float4*)(&inT[k][4]);
      a0 = fmaf(w, lo.x, a0); a1 = fmaf(w, lo.y, a1);
      a2 = fmaf(w, lo.z, a2); a3 = fmaf(w, lo.w, a3);
      a4 = fmaf(w, hi.x, a4); a5 = fmaf(w, hi.y, a5);
      a6 = fmaf(w, hi.z, a6); a7 = fmaf(w, hi.w, a7);
    }
    float bb = bias[c];
    a0 += bb; a1 += bb; a2 += bb; a3 += bb; a4 += bb; a5 += bb; a6 += bb; a7 += bb;
    if (RELU) {
      a0 = fmaxf(a0, 0.f); a1 = fmaxf(a1, 0.f); a2 = fmaxf(a2, 0.f); a3 = fmaxf(a3, 0.f);
      a4 = fmaxf(a4, 0.f); a5 = fmaxf(a5, 0.f); a6 = fmaxf(a6, 0.f); a7 = fmaxf(a7, 0.f);
    }
    outT[c][0] = a0; outT[c][1] = a1; outT[c][2] = a2; outT[c][3] = a3;
    outT[c][4] = a4; outT[c][5] = a5; outT[c][6] = a6; outT[c][7] = a7;
  }
}

__global__ __launch_bounds__(512) void cde_main(
    const float* __restrict__ x,     // (N,16,10)
    const int*   __restrict__ mask,  // (N)
    const float* __restrict__ We, const float* __restrict__ be,
    const float* __restrict__ b0, const float* __restrict__ b1,
    const float* __restrict__ b2, const float* __restrict__ b3,
    const float* __restrict__ W0t, const float* __restrict__ W1t,
    const float* __restrict__ W2t, const float* __restrict__ W3t,
    const float* __restrict__ dX,   // (46, N, 10)
    float* __restrict__ out)        // (N, 128)
{
  const int tid = threadIdx.x;
  const int n0 = blockIdx.x * RROWS;

  __shared__ __align__(16) float zT[E_DIM][RROWS];    // state, [col][row]
  __shared__ __align__(16) float zinT[E_DIM][RROWS];  // stage input
  __shared__ __align__(16) float kT[3][E_DIM][RROWS]; // k1,k2,k3
  __shared__ __align__(16) float Y0[H_DIM][RROWS];
  __shared__ __align__(16) float Y1[H_DIM][RROWS];
  __shared__ __align__(16) float G[RROWS][ED_DIM];    // tanh output, [row][col]
  __shared__ __align__(16) float dXs[RROWS][D_IN];

  // z0 = x[:,0,:] @ We^T + be
  for (int i = tid; i < RROWS * E_DIM; i += 512) {
    int e = i & 127, n = i >> 7;
    float acc = be[e];
#pragma unroll
    for (int d = 0; d < D_IN; ++d) acc = fmaf(x[(n0 + n) * 160 + d], We[e * 10 + d], acc);
    zT[e][n] = acc;
  }

  for (int s = 0; s < 15; ++s) {
    for (int st = 0; st < 4; ++st) {
      __syncthreads();
      // spline derivative for this stage's eval time
      int p = (st < 3) ? (3 * s + st) : ((s < 14) ? (3 * s + 3) : 45);
      if (tid < RROWS * D_IN)
        ((float*)dXs)[tid] = dX[p * (N_AG * D_IN) + n0 * D_IN + tid];

      const float (*in0)[RROWS] = (st == 0) ? (const float (*)[RROWS])zT
                                            : (const float (*)[RROWS])zinT;
      layer_fc<E_DIM, H_DIM, true>(W0t, b0, in0, Y0, tid);
      __syncthreads();
      layer_fc<H_DIM, H_DIM, true>(W1t, b1, (const float (*)[RROWS])Y0, Y1, tid);
      __syncthreads();
      layer_fc<H_DIM, H_DIM, true>(W2t, b2, (const float (*)[RROWS])Y1, Y0, tid);
      __syncthreads();

      // L3: y2 @ W3^T + b3 -> tanh -> G[row][col] (n-major for the vf contraction)
      for (int c = tid; c < ED_DIM; c += 512) {
        float a0 = 0, a1 = 0, a2 = 0, a3 = 0, a4 = 0, a5 = 0, a6 = 0, a7 = 0;
        const float* wp = W3t + c;
#pragma unroll 8
        for (int k = 0; k < H_DIM; ++k) {
          float w = wp[k * ED_DIM];
          float4 lo = *(const float4*)(&Y0[k][0]);
          float4 hi = *(const float4*)(&Y0[k][4]);
          a0 = fmaf(w, lo.x, a0); a1 = fmaf(w, lo.y, a1);
          a2 = fmaf(w, lo.z, a2); a3 = fmaf(w, lo.w, a3);
          a4 = fmaf(w, hi.x, a4); a5 = fmaf(w, hi.y, a5);
          a6 = fmaf(w, hi.z, a6); a7 = fmaf(w, hi.w, a7);
        }
        float bb = b3[c];
        G[0][c] = tanhf(a0 + bb); G[1][c] = tanhf(a1 + bb);
        G[2][c] = tanhf(a2 + bb); G[3][c] = tanhf(a3 + bb);
        G[4][c] = tanhf(a4 + bb); G[5][c] = tanhf(a5 + bb);
        G[6][c] = tanhf(a6 + bb); G[7][c] = tanhf(a7 + bb);
      }
      __syncthreads();

      // vf[n][e] = sum_d G[n][e*10+d] * dXs[n][d]; then RK4 bookkeeping (3/8 rule)
      {
        int e = tid & 127;
        int ng = tid >> 7;      // rows ng and ng+4
        int na = ng, nb = ng + 4;
        float v0 = 0.f, v1 = 0.f;
#pragma unroll
        for (int d = 0; d < D_IN; ++d) {
          v0 = fmaf(G[na][e * 10 + d], dXs[na][d], v0);
          v1 = fmaf(G[nb][e * 10 + d], dXs[nb][d], v1);
        }
        if (st == 0) {
          kT[0][e][na] = v0; kT[0][e][nb] = v1;
          zinT[e][na] = zT[e][na] + v0 * (1.0f / 3.0f);
          zinT[e][nb] = zT[e][nb] + v1 * (1.0f / 3.0f);
        } else if (st == 1) {
          kT[1][e][na] = v0; kT[1][e][nb] = v1;
          zinT[e][na] = zT[e][na] + v0 - kT[0][e][na] * (1.0f / 3.0f);
          zinT[e][nb] = zT[e][nb] + v1 - kT[0][e][nb] * (1.0f / 3.0f);
        } else if (st == 2) {
          kT[2][e][na] = v0; kT[2][e][nb] = v1;
          zinT[e][na] = zT[e][na] + kT[0][e][na] - kT[1][e][na] + v0;
          zinT[e][nb] = zT[e][nb] + kT[0][e][nb] - kT[1][e][nb] + v1;
        } else {
          zT[e][na] += (kT[0][e][na] + 3.0f * (kT[1][e][na] + kT[2][e][na]) + v0) * 0.125f;
          zT[e][nb] += (kT[0][e][nb] + 3.0f * (kT[1][e][nb] + kT[2][e][nb]) + v1) * 0.125f;
        }
      }
    }
  }
  __syncthreads();

  // masked output: (B, Amax, E) flat = (N, E)
  for (int i = tid; i < RROWS * E_DIM; i += 512) {
    int e = i & 127, n = i >> 7;
    out[(n0 + n) * E_DIM + e] = (mask[n0 + n] != 0) ? zT[e][n] : 0.0f;
  }
}

extern "C" void kernel_launch(void* const* d_in, const int* in_sizes, int n_in,
                              void* d_out, int out_size, void* d_ws, size_t ws_size,
                              hipStream_t stream) {
  const float* x    = (const float*)d_in[1];
  const int*   mask = (const int*)d_in[2];
  const float* We   = (const float*)d_in[3];
  const float* be   = (const float*)d_in[4];
  const float* W0   = (const float*)d_in[5];
  const float* b0   = (const float*)d_in[6];
  const float* W1   = (const float*)d_in[7];
  const float* b1   = (const float*)d_in[8];
  const float* W2   = (const float*)d_in[9];
  const float* b2   = (const float*)d_in[10];
  const float* W3   = (const float*)d_in[11];
  const float* b3   = (const float*)d_in[12];
  float* out = (float*)d_out;

  float* ws  = (float*)d_ws;
  float* W0t = ws + OFF_W0T;
  float* W1t = ws + OFF_W1T;
  float* W2t = ws + OFF_W2T;
  float* W3t = ws + OFF_W3T;
  float* dX  = ws + OFF_DX;

  transpose_k<<<(512 * 128 + 255) / 256, 256, 0, stream>>>(W0, W0t, 512, 128);
  transpose_k<<<(512 * 512 + 255) / 256, 256, 0, stream>>>(W1, W1t, 512, 512);
  transpose_k<<<(512 * 512 + 255) / 256, 256, 0, stream>>>(W2, W2t, 512, 512);
  transpose_k<<<(1280 * 512 + 255) / 256, 256, 0, stream>>>(W3, W3t, 1280, 512);
  spline_dx_k<<<(N_AG * D_IN + 255) / 256, 256, 0, stream>>>(x, dX);
  cde_main<<<256, 512, 0, stream>>>(x, mask, We, be, b0, b1, b2, b3,
                                    W0t, W1t, W2t, W3t, dX, out);
}